// Round 3
// baseline (58.471 us; speedup 1.0000x reference)
//
#include <hip/hip_runtime.h>
#include <math.h>

// ---------------------------------------------------------------------------
// N-pair Gaussian mixture log-likelihood, factorized form:
//   arg_ij(x) = g_i(x) + g_j(x) + c_ij,  g_i(x) = -0.5 x'prec_i x + x'rhs_i
//   pdf(x)    = u' E u,  u_i = exp(g_i(x)),  E_ij = exp(c_ij + 64 ln2)  [scaled]
//   out       = mean_n( log pdf_n ) + log z_last   (scale folded into Kconst)
// Two kernels: setup (1 block) and main (grid + deterministic ticket finale).
// ---------------------------------------------------------------------------

#define LOG2E_F 1.4426950408889634f
#define LN2_F   0.6931471805599453f
#define LN2PI_F 1.8378770664093453f   // ln(2*pi)

// ws layout (float offsets)
#define WS_COEF 0      // 16 components * 48 floats: 36 quad + 8 lin (log2e-scaled), 4 pad
#define WS_ES   768    // 136 packed lower-tri pair weights: diag=E'_ii, offdiag=2*E'_ij
#define WS_K    960    // Kconst = log z_last - 64 ln2
#define WS_CNT  961    // ticket counter (int)
#define WS_PART 1024   // per-block partial sums (nb <= ~2048)

__device__ __forceinline__ float fexp2(float x) {
#if __has_builtin(__builtin_amdgcn_exp2f)
  return __builtin_amdgcn_exp2f(x);
#else
  return exp2f(x);
#endif
}
__device__ __forceinline__ float flog2(float x) {
#if __has_builtin(__builtin_amdgcn_logf)
  return __builtin_amdgcn_logf(x);
#else
  return log2f(x);
#endif
}

// Cholesky: A = C C^T (lower). Only lower triangle of A read. Fully unrolled.
__device__ __forceinline__ void chol8(const float (*A)[8], float (*C)[8]) {
  #pragma unroll
  for (int d = 0; d < 8; ++d) {
    float s = A[d][d];
    #pragma unroll
    for (int m = 0; m < 8; ++m) if (m < d) s -= C[d][m] * C[d][m];
    float cd = sqrtf(s);
    C[d][d] = cd;
    float inv = 1.f / cd;
    #pragma unroll
    for (int e = 0; e < 8; ++e) if (e > d) {
      float t = A[e][d];
      #pragma unroll
      for (int m = 0; m < 8; ++m) if (m < d) t -= C[e][m] * C[d][m];
      C[e][d] = t * inv;
    }
  }
}

// ---------------------------------------------------------------------------
// Kernel A: all setup in one block.
//  phase 1 (threads 0-15): prec_k = inv(tril(L)tril(L)'+I), rhs_k -> LDS
//  phase 2 (all 256):      pair constants -> coef rows, packed symmetric E',
//                          Kconst, ticket-counter reset
// ---------------------------------------------------------------------------
__global__ __launch_bounds__(256) void gm_setup(const float* __restrict__ mu,
                                                const float* __restrict__ L,
                                                const float* __restrict__ wts,
                                                float* __restrict__ ws) {
  __shared__ float sp[16][72];   // prec[64] + rhs[8] per component
  int tid = threadIdx.x;
  if (tid == 0) ((int*)ws)[WS_CNT] = 0;   // reset finale ticket each call
  if (tid < 16) {
    int k = tid;
    float Lt[8][8];
    #pragma unroll
    for (int d = 0; d < 8; ++d)
      #pragma unroll
      for (int e = 0; e < 8; ++e)
        Lt[d][e] = (e <= d) ? L[k * 64 + d * 8 + e] : 0.f;
    float A[8][8];
    #pragma unroll
    for (int d = 0; d < 8; ++d)
      #pragma unroll
      for (int e = 0; e <= d; ++e) {
        float s = (d == e) ? 1.f : 0.f;
        #pragma unroll
        for (int m = 0; m < 8; ++m) s += Lt[d][m] * Lt[e][m];
        A[d][e] = s;
        A[e][d] = s;
      }
    float C[8][8];
    chol8(A, C);
    float Ci[8][8];
    #pragma unroll
    for (int d = 0; d < 8; ++d) Ci[d][d] = 1.f / C[d][d];
    #pragma unroll
    for (int e = 0; e < 8; ++e)
      #pragma unroll
      for (int d = 0; d < 8; ++d) if (d > e) {
        float s = 0.f;
        #pragma unroll
        for (int m = 0; m < 8; ++m) if (m >= e && m < d) s += C[d][m] * Ci[m][e];
        Ci[d][e] = -s * Ci[d][d];
      }
    #pragma unroll
    for (int a = 0; a < 8; ++a)
      #pragma unroll
      for (int b = 0; b < 8; ++b) {
        float s = 0.f;
        #pragma unroll
        for (int m = 0; m < 8; ++m) if (m >= a && m >= b) s += Ci[m][a] * Ci[m][b];
        sp[k][a * 8 + b] = s;
      }
    #pragma unroll
    for (int d = 0; d < 8; ++d) {
      float s = 0.f;
      #pragma unroll
      for (int e = 0; e < 8; ++e) s += sp[k][d * 8 + e] * mu[k * 8 + e];
      sp[k][64 + d] = s;
    }
  }
  __syncthreads();

  int p = tid;
  int i = p >> 4, j = p & 15;
  const float* pi = sp[i];
  const float* pj = sp[j];
  float P[8][8], rp[8];
  #pragma unroll
  for (int d = 0; d < 8; ++d) {
    #pragma unroll
    for (int e = 0; e < 8; ++e) P[d][e] = pi[d * 8 + e] + pj[d * 8 + e];
    rp[d] = pi[64 + d] + pj[64 + d];
  }
  float U[8][8];
  chol8(P, U);
  float logdet = 0.f;
  #pragma unroll
  for (int d = 0; d < 8; ++d) logdet += logf(U[d][d]);
  logdet *= 2.f;
  float zf[8];
  #pragma unroll
  for (int d = 0; d < 8; ++d) {
    float s = rp[d];
    #pragma unroll
    for (int m = 0; m < 8; ++m) if (m < d) s -= U[d][m] * zf[m];
    zf[d] = s / U[d][d];
  }
  float y[8];
  #pragma unroll
  for (int dd = 7; dd >= 0; --dd) {
    float s = zf[dd];
    #pragma unroll
    for (int m = 0; m < 8; ++m) if (m > dd) s -= U[m][dd] * y[m];
    y[dd] = s / U[dd][dd];
  }
  float muPmu = 0.f;
  #pragma unroll
  for (int d = 0; d < 8; ++d) muPmu += rp[d] * y[d];
  // c'_ij = -0.5 mu'Pmu + 0.5 log det P - 32 ln(2pi) + ln w_i + ln w_j + 64 ln2
  float c = -0.5f * muPmu + 0.5f * logdet - 32.f * LN2PI_F
          + logf(wts[i]) + logf(wts[j]) + 64.f * LN2_F;
  float Ev = expf(c);
  if (j <= i)   // packed lower triangle; fold the symmetry factor 2 off-diag
    ws[WS_ES + i * (i + 1) / 2 + j] = (i == j) ? Ev : 2.f * Ev;
  if (i == j) { // per-component main-loop coefficients, pre-scaled by log2(e)
    float* c0 = ws + WS_COEF + i * 48;
    int q = 0;
    #pragma unroll
    for (int d = 0; d < 8; ++d)
      #pragma unroll
      for (int e = d; e < 8; ++e) {
        float v = (d == e) ? -0.5f * pi[d * 8 + e] : -pi[d * 8 + e];
        c0[q++] = v * LOG2E_F;
      }
    #pragma unroll
    for (int d = 0; d < 8; ++d) c0[36 + d] = pi[64 + d] * LOG2E_F;
    c0[44] = 0.f; c0[45] = 0.f; c0[46] = 0.f; c0[47] = 0.f;
  }
  if (p == 255) ws[WS_K] = 0.5f * logdet - 32.f * LN2PI_F - 64.f * LN2_F;
}

// ---------------------------------------------------------------------------
// Kernel B: main N-loop + deterministic ticket finale.
// One x per thread; coefficient reads are wave-uniform (expect SMEM scalar).
// ---------------------------------------------------------------------------
__global__ __launch_bounds__(256) void gm_main(const float* __restrict__ X,
                                               float* __restrict__ ws,
                                               int N, int nb, float invN) {
  int gid = blockIdx.x * 256 + threadIdx.x;
  const float* __restrict__ coef = ws + WS_COEF;
  const float* __restrict__ Es = ws + WS_ES;
  float lsum = 0.f;
  if (gid < N) {
    const float4* Xv = reinterpret_cast<const float4*>(X) + (size_t)gid * 2;
    float4 xa = Xv[0];
    float4 xb = Xv[1];
    float pr[44];
    pr[36] = xa.x; pr[37] = xa.y; pr[38] = xa.z; pr[39] = xa.w;
    pr[40] = xb.x; pr[41] = xb.y; pr[42] = xb.z; pr[43] = xb.w;
    {
      int q = 0;
      #pragma unroll
      for (int d = 0; d < 8; ++d)
        #pragma unroll
        for (int e = d; e < 8; ++e) pr[q++] = pr[36 + d] * pr[36 + e];
    }
    float u[16];
    #pragma unroll 4
    for (int i = 0; i < 16; ++i) {
      const float* c = coef + i * 48;
      float a0 = 0.f, a1 = 0.f, a2 = 0.f, a3 = 0.f;
      #pragma unroll
      for (int q = 0; q < 44; q += 4) {
        a0 = fmaf(c[q + 0], pr[q + 0], a0);
        a1 = fmaf(c[q + 1], pr[q + 1], a1);
        a2 = fmaf(c[q + 2], pr[q + 2], a2);
        a3 = fmaf(c[q + 3], pr[q + 3], a3);
      }
      u[i] = fexp2((a0 + a1) + (a2 + a3));  // u_i = e^{g_i}, log2e pre-folded
    }
    // pdf = sum_i u_i * ( sum_{j<i} 2E_ij u_j + E_ii u_i )   [E symmetric]
    float pdf = 0.f;
    #pragma unroll
    for (int i = 0; i < 16; ++i) {
      const float* e = Es + i * (i + 1) / 2;
      float t0 = 0.f, t1 = 0.f;
      #pragma unroll
      for (int j = 0; j + 1 < i; j += 2) {
        t0 = fmaf(e[j + 0], u[j + 0], t0);
        t1 = fmaf(e[j + 1], u[j + 1], t1);
      }
      if (i & 1) t0 = fmaf(e[i - 1], u[i - 1], t0);
      t0 = fmaf(e[i], u[i], t0 + t1);      // diagonal term
      pdf = fmaf(u[i], t0, pdf);
    }
    lsum = flog2(pdf);
  }
  // deterministic block reduction of sum(log2 pdf)
  #pragma unroll
  for (int off = 32; off > 0; off >>= 1) lsum += __shfl_down(lsum, off, 64);
  __shared__ float wsum[4];
  __shared__ int lastflag;
  int lane = threadIdx.x & 63, wid = threadIdx.x >> 6;
  if (lane == 0) wsum[wid] = lsum;
  __syncthreads();
  float* partials = ws + WS_PART;
  if (threadIdx.x == 0) {
    partials[blockIdx.x] = (wsum[0] + wsum[1]) + (wsum[2] + wsum[3]);
    __threadfence();                                   // release partial
    int old = atomicAdd((int*)ws + WS_CNT, 1);         // device-scope ticket
    lastflag = (old == nb - 1);
  }
  __syncthreads();
  if (lastflag) {
    __threadfence();                                   // acquire all partials
    float s = 0.f;
    for (int t = threadIdx.x; t < nb; t += 256) s += partials[t];  // fixed order
    #pragma unroll
    for (int off = 32; off > 0; off >>= 1) s += __shfl_down(s, off, 64);
    if (lane == 0) wsum[wid] = s;
    __syncthreads();
    if (threadIdx.x == 0) {
      float tot = (wsum[0] + wsum[1]) + (wsum[2] + wsum[3]);
      // mean(ln pdf_true) + ln z_last = ln2 * mean(log2 pdf_scaled) + Kconst
      ((float*)ws)[WS_PART - 1] = 0.f;  // (unused scratch touch, keeps ws self-init)
      *((float*)nullptr == nullptr ? (float*)0 : (float*)0);  // no-op guard removed below
    }
  }
  // NOTE: out-write moved below to keep a single exit path
}

// The finale above needs d_out; simplest correct form: do the out-write in the
// same place. Re-declared as a separate writer to keep the kernel signature
// clean was worse — so gm_main2 is the real main kernel used by kernel_launch.
__global__ __launch_bounds__(256) void gm_main2(const float* __restrict__ X,
                                                float* __restrict__ ws,
                                                float* __restrict__ out,
                                                int N, int nb, float invN) {
  int gid = blockIdx.x * 256 + threadIdx.x;
  const float* __restrict__ coef = ws + WS_COEF;
  const float* __restrict__ Es = ws + WS_ES;
  float lsum = 0.f;
  if (gid < N) {
    const float4* Xv = reinterpret_cast<const float4*>(X) + (size_t)gid * 2;
    float4 xa = Xv[0];
    float4 xb = Xv[1];
    float pr[44];
    pr[36] = xa.x; pr[37] = xa.y; pr[38] = xa.z; pr[39] = xa.w;
    pr[40] = xb.x; pr[41] = xb.y; pr[42] = xb.z; pr[43] = xb.w;
    {
      int q = 0;
      #pragma unroll
      for (int d = 0; d < 8; ++d)
        #pragma unroll
        for (int e = d; e < 8; ++e) pr[q++] = pr[36 + d] * pr[36 + e];
    }
    float u[16];
    #pragma unroll 4
    for (int i = 0; i < 16; ++i) {
      const float* c = coef + i * 48;
      float a0 = 0.f, a1 = 0.f, a2 = 0.f, a3 = 0.f;
      #pragma unroll
      for (int q = 0; q < 44; q += 4) {
        a0 = fmaf(c[q + 0], pr[q + 0], a0);
        a1 = fmaf(c[q + 1], pr[q + 1], a1);
        a2 = fmaf(c[q + 2], pr[q + 2], a2);
        a3 = fmaf(c[q + 3], pr[q + 3], a3);
      }
      u[i] = fexp2((a0 + a1) + (a2 + a3));
    }
    float pdf = 0.f;
    #pragma unroll
    for (int i = 0; i < 16; ++i) {
      const float* e = Es + i * (i + 1) / 2;
      float t0 = 0.f, t1 = 0.f;
      #pragma unroll
      for (int j = 0; j + 1 < i; j += 2) {
        t0 = fmaf(e[j + 0], u[j + 0], t0);
        t1 = fmaf(e[j + 1], u[j + 1], t1);
      }
      if (i & 1) t0 = fmaf(e[i - 1], u[i - 1], t0);
      t0 = fmaf(e[i], u[i], t0 + t1);
      pdf = fmaf(u[i], t0, pdf);
    }
    lsum = flog2(pdf);
  }
  #pragma unroll
  for (int off = 32; off > 0; off >>= 1) lsum += __shfl_down(lsum, off, 64);
  __shared__ float wsum[4];
  __shared__ int lastflag;
  int lane = threadIdx.x & 63, wid = threadIdx.x >> 6;
  if (lane == 0) wsum[wid] = lsum;
  __syncthreads();
  float* partials = ws + WS_PART;
  if (threadIdx.x == 0) {
    partials[blockIdx.x] = (wsum[0] + wsum[1]) + (wsum[2] + wsum[3]);
    __threadfence();
    int old = atomicAdd((int*)ws + WS_CNT, 1);
    lastflag = (old == nb - 1) ? 1 : 0;
  }
  __syncthreads();
  if (lastflag) {
    __threadfence();
    float s = 0.f;
    for (int t = threadIdx.x; t < nb; t += 256) s += partials[t];
    #pragma unroll
    for (int off = 32; off > 0; off >>= 1) s += __shfl_down(s, off, 64);
    if (lane == 0) wsum[wid] = s;
    __syncthreads();
    if (threadIdx.x == 0) {
      float tot = (wsum[0] + wsum[1]) + (wsum[2] + wsum[3]);
      out[0] = tot * LN2_F * invN + ws[WS_K];
    }
  }
}

extern "C" void kernel_launch(void* const* d_in, const int* in_sizes, int n_in,
                              void* d_out, int out_size, void* d_ws, size_t ws_size,
                              hipStream_t stream) {
  const float* X = (const float*)d_in[0];
  const float* mu = (const float*)d_in[1];
  const float* L = (const float*)d_in[2];
  const float* wts = (const float*)d_in[3];
  // d_in[4] ("it") is unused by the reference math.
  float* ws = (float*)d_ws;
  float* out = (float*)d_out;
  int N = in_sizes[0] / 8;
  int nb = (N + 255) / 256;
  gm_setup<<<1, 256, 0, stream>>>(mu, L, wts, ws);
  gm_main2<<<nb, 256, 0, stream>>>(X, ws, out, N, nb, 1.0f / (float)N);
}

// Round 4
// 33.732 us; speedup vs baseline: 1.7334x; 1.7334x over previous
//
#include <hip/hip_runtime.h>
#include <math.h>

// ---------------------------------------------------------------------------
// N-pair Gaussian mixture log-likelihood, factorized form:
//   arg_ij(x) = g_i(x) + g_j(x) + c_ij,  g_i(x) = -0.5 x'prec_i x + x'rhs_i
//   pdf(x)    = u' E u,  u_i = exp(g_i(x)),  E_ij = exp(c_ij + 64 ln2)  [scaled]
//   out       = mean_n( log pdf_n ) + log z_last   (scale folded into Kconst)
// Three kernels: setup (1 block), main (4 pts/thread, pure compute),
// final (1 block). No atomics, no fences -> deterministic, no cache storms.
// ---------------------------------------------------------------------------

#define LOG2E_F 1.4426950408889634f
#define LN2_F   0.6931471805599453f
#define LN2PI_F 1.8378770664093453f   // ln(2*pi)

// ws layout (float offsets)
#define WS_COEF 0      // 16 rows * 48: per d {lin_d, Q_dd..Q_d7} *log2e; 44 used
#define WS_ES   768    // 136 packed lower-tri pair weights: diag=E'_ii, off=2E'_ij
#define WS_K    960    // Kconst = log z_last - 64 ln2
#define WS_PART 1024   // per-block partial sums (nb <= ~1024)

__device__ __forceinline__ float fexp2(float x) {
#if __has_builtin(__builtin_amdgcn_exp2f)
  return __builtin_amdgcn_exp2f(x);
#else
  return exp2f(x);
#endif
}
__device__ __forceinline__ float flog2(float x) {
#if __has_builtin(__builtin_amdgcn_logf)
  return __builtin_amdgcn_logf(x);
#else
  return log2f(x);
#endif
}

// Cholesky: A = C C^T (lower). Only lower triangle of A read. Fully unrolled.
__device__ __forceinline__ void chol8(const float (*A)[8], float (*C)[8]) {
  #pragma unroll
  for (int d = 0; d < 8; ++d) {
    float s = A[d][d];
    #pragma unroll
    for (int m = 0; m < 8; ++m) if (m < d) s -= C[d][m] * C[d][m];
    float cd = sqrtf(s);
    C[d][d] = cd;
    float inv = 1.f / cd;
    #pragma unroll
    for (int e = 0; e < 8; ++e) if (e > d) {
      float t = A[e][d];
      #pragma unroll
      for (int m = 0; m < 8; ++m) if (m < d) t -= C[e][m] * C[d][m];
      C[e][d] = t * inv;
    }
  }
}

// ---------------------------------------------------------------------------
// Kernel A: all setup in one block.
//  phase 1 (threads 0-15): prec_k = inv(tril(L)tril(L)'+I), rhs_k -> LDS
//  phase 2 (all 256):      pair constants -> coef rows, packed symmetric E', K
// ---------------------------------------------------------------------------
__global__ __launch_bounds__(256) void gm_setup(const float* __restrict__ mu,
                                                const float* __restrict__ L,
                                                const float* __restrict__ wts,
                                                float* __restrict__ ws) {
  __shared__ float sp[16][72];   // prec[64] + rhs[8] per component
  int tid = threadIdx.x;
  if (tid < 16) {
    int k = tid;
    float Lt[8][8];
    #pragma unroll
    for (int d = 0; d < 8; ++d)
      #pragma unroll
      for (int e = 0; e < 8; ++e)
        Lt[d][e] = (e <= d) ? L[k * 64 + d * 8 + e] : 0.f;
    float A[8][8];
    #pragma unroll
    for (int d = 0; d < 8; ++d)
      #pragma unroll
      for (int e = 0; e <= d; ++e) {
        float s = (d == e) ? 1.f : 0.f;
        #pragma unroll
        for (int m = 0; m < 8; ++m) s += Lt[d][m] * Lt[e][m];
        A[d][e] = s;
        A[e][d] = s;
      }
    float C[8][8];
    chol8(A, C);
    float Ci[8][8];
    #pragma unroll
    for (int d = 0; d < 8; ++d) Ci[d][d] = 1.f / C[d][d];
    #pragma unroll
    for (int e = 0; e < 8; ++e)
      #pragma unroll
      for (int d = 0; d < 8; ++d) if (d > e) {
        float s = 0.f;
        #pragma unroll
        for (int m = 0; m < 8; ++m) if (m >= e && m < d) s += C[d][m] * Ci[m][e];
        Ci[d][e] = -s * Ci[d][d];
      }
    #pragma unroll
    for (int a = 0; a < 8; ++a)
      #pragma unroll
      for (int b = 0; b < 8; ++b) {
        float s = 0.f;
        #pragma unroll
        for (int m = 0; m < 8; ++m) if (m >= a && m >= b) s += Ci[m][a] * Ci[m][b];
        sp[k][a * 8 + b] = s;
      }
    #pragma unroll
    for (int d = 0; d < 8; ++d) {
      float s = 0.f;
      #pragma unroll
      for (int e = 0; e < 8; ++e) s += sp[k][d * 8 + e] * mu[k * 8 + e];
      sp[k][64 + d] = s;
    }
  }
  __syncthreads();

  int p = tid;
  int i = p >> 4, j = p & 15;
  const float* pi = sp[i];
  const float* pj = sp[j];
  float P[8][8], rp[8];
  #pragma unroll
  for (int d = 0; d < 8; ++d) {
    #pragma unroll
    for (int e = 0; e < 8; ++e) P[d][e] = pi[d * 8 + e] + pj[d * 8 + e];
    rp[d] = pi[64 + d] + pj[64 + d];
  }
  float U[8][8];
  chol8(P, U);
  float logdet = 0.f;
  #pragma unroll
  for (int d = 0; d < 8; ++d) logdet += logf(U[d][d]);
  logdet *= 2.f;
  float zf[8];
  #pragma unroll
  for (int d = 0; d < 8; ++d) {
    float s = rp[d];
    #pragma unroll
    for (int m = 0; m < 8; ++m) if (m < d) s -= U[d][m] * zf[m];
    zf[d] = s / U[d][d];
  }
  float y[8];
  #pragma unroll
  for (int dd = 7; dd >= 0; --dd) {
    float s = zf[dd];
    #pragma unroll
    for (int m = 0; m < 8; ++m) if (m > dd) s -= U[m][dd] * y[m];
    y[dd] = s / U[dd][dd];
  }
  float muPmu = 0.f;
  #pragma unroll
  for (int d = 0; d < 8; ++d) muPmu += rp[d] * y[d];
  // c'_ij = -0.5 mu'Pmu + 0.5 log det P - 32 ln(2pi) + ln w_i + ln w_j + 64 ln2
  float c = -0.5f * muPmu + 0.5f * logdet - 32.f * LN2PI_F
          + logf(wts[i]) + logf(wts[j]) + 64.f * LN2_F;
  float Ev = expf(c);
  if (j <= i)   // packed lower triangle; symmetry factor 2 folded off-diagonal
    ws[WS_ES + i * (i + 1) / 2 + j] = (i == j) ? Ev : 2.f * Ev;
  if (i == j) { // main-loop coefficient row, interleaved {lin_d, Q_dd..Q_d7}
    float* c0 = ws + WS_COEF + i * 48;
    int q = 0;
    #pragma unroll
    for (int d = 0; d < 8; ++d) {
      c0[q++] = pi[64 + d] * LOG2E_F;                 // lin_d
      #pragma unroll
      for (int e = d; e < 8; ++e) {
        float v = (d == e) ? -0.5f * pi[d * 8 + e] : -pi[d * 8 + e];
        c0[q++] = v * LOG2E_F;                        // Q_de
      }
    }
    c0[44] = 0.f; c0[45] = 0.f; c0[46] = 0.f; c0[47] = 0.f;
  }
  if (p == 255) ws[WS_K] = 0.5f * logdet - 32.f * LN2PI_F - 64.f * LN2_F;
}

// ---------------------------------------------------------------------------
// Kernel B: main N-loop, 4 points per thread. Coefficients read through a
// CONST restrict pointer (uniform addresses -> SMEM s_load); partials written
// through a disjoint restrict pointer. No atomics, no fences.
// ---------------------------------------------------------------------------
__global__ __launch_bounds__(256) void gm_main(const float* __restrict__ X,
                                               const float* __restrict__ cf,
                                               float* __restrict__ partials,
                                               int N) {
  const int t = threadIdx.x;
  const int base = blockIdx.x * 1024 + t;
  float xs[4][8];
  bool act[4];
  #pragma unroll
  for (int g = 0; g < 4; ++g) {
    int gid = base + g * 256;
    act[g] = gid < N;
    int src = act[g] ? gid : 0;            // clamp: X[0..7] is valid memory
    const float4* Xv = reinterpret_cast<const float4*>(X) + (size_t)src * 2;
    float4 a = Xv[0], b = Xv[1];
    xs[g][0] = a.x; xs[g][1] = a.y; xs[g][2] = a.z; xs[g][3] = a.w;
    xs[g][4] = b.x; xs[g][5] = b.y; xs[g][6] = b.z; xs[g][7] = b.w;
  }

  // u[g][i] = exp(g_i(x_g)) with log2e pre-folded into coefficients
  float u[4][16];
  #pragma unroll
  for (int i = 0; i < 16; ++i) {
    const float* c = cf + WS_COEF + i * 48;
    float g0 = 0.f, g1 = 0.f, g2 = 0.f, g3 = 0.f;
    int q = 0;
    #pragma unroll
    for (int d = 0; d < 8; ++d) {
      float lc = c[q++];
      float r0 = lc, r1 = lc, r2 = lc, r3 = lc;   // lin_d
      #pragma unroll
      for (int e = d; e < 8; ++e) {
        float cc = c[q++];
        r0 = fmaf(cc, xs[0][e], r0);
        r1 = fmaf(cc, xs[1][e], r1);
        r2 = fmaf(cc, xs[2][e], r2);
        r3 = fmaf(cc, xs[3][e], r3);
      }
      g0 = fmaf(xs[0][d], r0, g0);
      g1 = fmaf(xs[1][d], r1, g1);
      g2 = fmaf(xs[2][d], r2, g2);
      g3 = fmaf(xs[3][d], r3, g3);
    }
    u[0][i] = fexp2(g0);
    u[1][i] = fexp2(g1);
    u[2][i] = fexp2(g2);
    u[3][i] = fexp2(g3);
  }

  // pdf = sum_i u_i * ( sum_{j<i} 2E_ij u_j + E_ii u_i )   [E symmetric]
  float p0 = 0.f, p1 = 0.f, p2 = 0.f, p3 = 0.f;
  #pragma unroll
  for (int i = 0; i < 16; ++i) {
    const float* e = cf + WS_ES + (i * (i + 1)) / 2;
    float s0 = 0.f, s1 = 0.f, s2 = 0.f, s3 = 0.f;
    #pragma unroll
    for (int j = 0; j <= i; ++j) {
      float ev = e[j];
      s0 = fmaf(ev, u[0][j], s0);
      s1 = fmaf(ev, u[1][j], s1);
      s2 = fmaf(ev, u[2][j], s2);
      s3 = fmaf(ev, u[3][j], s3);
    }
    p0 = fmaf(u[0][i], s0, p0);
    p1 = fmaf(u[1][i], s1, p1);
    p2 = fmaf(u[2][i], s2, p2);
    p3 = fmaf(u[3][i], s3, p3);
  }
  float lsum = 0.f;
  if (act[0]) lsum += flog2(p0);
  if (act[1]) lsum += flog2(p1);
  if (act[2]) lsum += flog2(p2);
  if (act[3]) lsum += flog2(p3);

  // deterministic block reduction of sum(log2 pdf)
  #pragma unroll
  for (int off = 32; off > 0; off >>= 1) lsum += __shfl_down(lsum, off, 64);
  __shared__ float wsum[4];
  int lane = threadIdx.x & 63, wid = threadIdx.x >> 6;
  if (lane == 0) wsum[wid] = lsum;
  __syncthreads();
  if (threadIdx.x == 0)
    partials[blockIdx.x] = (wsum[0] + wsum[1]) + (wsum[2] + wsum[3]);
}

// ---------------------------------------------------------------------------
// Kernel C: deterministic final reduction (fixed-order strided + tree)
// ---------------------------------------------------------------------------
__global__ __launch_bounds__(256) void gm_final(const float* __restrict__ ws,
                                                float* __restrict__ out,
                                                int nb, float invN) {
  const float* partials = ws + WS_PART;
  float s = 0.f;
  for (int t = threadIdx.x; t < nb; t += 256) s += partials[t];
  #pragma unroll
  for (int off = 32; off > 0; off >>= 1) s += __shfl_down(s, off, 64);
  __shared__ float wsum[4];
  int lane = threadIdx.x & 63, wid = threadIdx.x >> 6;
  if (lane == 0) wsum[wid] = s;
  __syncthreads();
  if (threadIdx.x == 0) {
    float tot = (wsum[0] + wsum[1]) + (wsum[2] + wsum[3]);
    // mean(ln pdf_true) + ln z_last = ln2 * mean(log2 pdf_scaled) + Kconst
    out[0] = tot * LN2_F * invN + ws[WS_K];
  }
}

extern "C" void kernel_launch(void* const* d_in, const int* in_sizes, int n_in,
                              void* d_out, int out_size, void* d_ws, size_t ws_size,
                              hipStream_t stream) {
  const float* X = (const float*)d_in[0];
  const float* mu = (const float*)d_in[1];
  const float* L = (const float*)d_in[2];
  const float* wts = (const float*)d_in[3];
  // d_in[4] ("it") is unused by the reference math.
  float* ws = (float*)d_ws;
  float* out = (float*)d_out;
  int N = in_sizes[0] / 8;
  int nb = (N + 1023) / 1024;            // 4 points per thread, 256 threads
  gm_setup<<<1, 256, 0, stream>>>(mu, L, wts, ws);
  gm_main<<<nb, 256, 0, stream>>>(X, ws, ws + WS_PART, N);
  gm_final<<<1, 256, 0, stream>>>(ws, out, nb, 1.0f / (float)N);
}

// Round 5
// 25.289 us; speedup vs baseline: 2.3121x; 1.3339x over previous
//
#include <hip/hip_runtime.h>
#include <math.h>

// ---------------------------------------------------------------------------
// N-pair Gaussian mixture log-likelihood, factorized form:
//   arg_ij(x) = g_i(x) + g_j(x) + c_ij,  g_i(x) = -0.5 x'prec_i x + x'rhs_i
//   pdf(x)    = u' E u,  u_i = exp(g_i(x)),  E_ij = exp(c_ij + 64 ln2)  [scaled]
//   out       = mean_n( log pdf_n ) + log z_last   (scale folded into Kconst)
// Three kernels: setup (1 block), main (4 pts/thread, LDS-staged constants),
// final (1 block). No atomics, no fences -> deterministic.
// ---------------------------------------------------------------------------

#define LOG2E_F 1.4426950408889634f
#define LN2_F   0.6931471805599453f
#define LN2PI_F 1.8378770664093453f   // ln(2*pi)

// ws layout (float offsets) -- COEF and ES contiguous so main stages [0,904)
#define WS_COEF 0      // 16 rows * 48: per d {lin_d, Q_dd..Q_d7} *log2e; 44 used
#define WS_ES   768    // 136 packed lower-tri pair weights: diag=E'_ii, off=2E'_ij
#define WS_NSC  904    // total staged floats
#define WS_K    960    // Kconst = log z_last - 64 ln2
#define WS_PART 1024   // per-block partial sums (nb <= ~1024)

__device__ __forceinline__ float fexp2(float x) {
#if __has_builtin(__builtin_amdgcn_exp2f)
  return __builtin_amdgcn_exp2f(x);
#else
  return exp2f(x);
#endif
}
__device__ __forceinline__ float flog2(float x) {
#if __has_builtin(__builtin_amdgcn_logf)
  return __builtin_amdgcn_logf(x);
#else
  return log2f(x);
#endif
}

// Cholesky: A = C C^T (lower). Only lower triangle of A read. Fully unrolled.
__device__ __forceinline__ void chol8(const float (*A)[8], float (*C)[8]) {
  #pragma unroll
  for (int d = 0; d < 8; ++d) {
    float s = A[d][d];
    #pragma unroll
    for (int m = 0; m < 8; ++m) if (m < d) s -= C[d][m] * C[d][m];
    float cd = sqrtf(s);
    C[d][d] = cd;
    float inv = 1.f / cd;
    #pragma unroll
    for (int e = 0; e < 8; ++e) if (e > d) {
      float t = A[e][d];
      #pragma unroll
      for (int m = 0; m < 8; ++m) if (m < d) t -= C[e][m] * C[d][m];
      C[e][d] = t * inv;
    }
  }
}

// ---------------------------------------------------------------------------
// Kernel A: all setup in one block.
//  phase 1 (threads 0-15): prec_k = inv(tril(L)tril(L)'+I), rhs_k -> LDS
//  phase 2 (all 256):      pair constants -> coef rows, packed symmetric E', K
// ---------------------------------------------------------------------------
__global__ __launch_bounds__(256) void gm_setup(const float* __restrict__ mu,
                                                const float* __restrict__ L,
                                                const float* __restrict__ wts,
                                                float* __restrict__ ws) {
  __shared__ float sp[16][72];   // prec[64] + rhs[8] per component
  int tid = threadIdx.x;
  if (tid < 16) {
    int k = tid;
    float Lt[8][8];
    #pragma unroll
    for (int d = 0; d < 8; ++d)
      #pragma unroll
      for (int e = 0; e < 8; ++e)
        Lt[d][e] = (e <= d) ? L[k * 64 + d * 8 + e] : 0.f;
    float A[8][8];
    #pragma unroll
    for (int d = 0; d < 8; ++d)
      #pragma unroll
      for (int e = 0; e <= d; ++e) {
        float s = (d == e) ? 1.f : 0.f;
        #pragma unroll
        for (int m = 0; m < 8; ++m) s += Lt[d][m] * Lt[e][m];
        A[d][e] = s;
        A[e][d] = s;
      }
    float C[8][8];
    chol8(A, C);
    float Ci[8][8];
    #pragma unroll
    for (int d = 0; d < 8; ++d) Ci[d][d] = 1.f / C[d][d];
    #pragma unroll
    for (int e = 0; e < 8; ++e)
      #pragma unroll
      for (int d = 0; d < 8; ++d) if (d > e) {
        float s = 0.f;
        #pragma unroll
        for (int m = 0; m < 8; ++m) if (m >= e && m < d) s += C[d][m] * Ci[m][e];
        Ci[d][e] = -s * Ci[d][d];
      }
    #pragma unroll
    for (int a = 0; a < 8; ++a)
      #pragma unroll
      for (int b = 0; b < 8; ++b) {
        float s = 0.f;
        #pragma unroll
        for (int m = 0; m < 8; ++m) if (m >= a && m >= b) s += Ci[m][a] * Ci[m][b];
        sp[k][a * 8 + b] = s;
      }
    #pragma unroll
    for (int d = 0; d < 8; ++d) {
      float s = 0.f;
      #pragma unroll
      for (int e = 0; e < 8; ++e) s += sp[k][d * 8 + e] * mu[k * 8 + e];
      sp[k][64 + d] = s;
    }
  }
  __syncthreads();

  int p = tid;
  int i = p >> 4, j = p & 15;
  const float* pi = sp[i];
  const float* pj = sp[j];
  float P[8][8], rp[8];
  #pragma unroll
  for (int d = 0; d < 8; ++d) {
    #pragma unroll
    for (int e = 0; e < 8; ++e) P[d][e] = pi[d * 8 + e] + pj[d * 8 + e];
    rp[d] = pi[64 + d] + pj[64 + d];
  }
  float U[8][8];
  chol8(P, U);
  float logdet = 0.f;
  #pragma unroll
  for (int d = 0; d < 8; ++d) logdet += logf(U[d][d]);
  logdet *= 2.f;
  float zf[8];
  #pragma unroll
  for (int d = 0; d < 8; ++d) {
    float s = rp[d];
    #pragma unroll
    for (int m = 0; m < 8; ++m) if (m < d) s -= U[d][m] * zf[m];
    zf[d] = s / U[d][d];
  }
  float y[8];
  #pragma unroll
  for (int dd = 7; dd >= 0; --dd) {
    float s = zf[dd];
    #pragma unroll
    for (int m = 0; m < 8; ++m) if (m > dd) s -= U[m][dd] * y[m];
    y[dd] = s / U[dd][dd];
  }
  float muPmu = 0.f;
  #pragma unroll
  for (int d = 0; d < 8; ++d) muPmu += rp[d] * y[d];
  // c'_ij = -0.5 mu'Pmu + 0.5 log det P - 32 ln(2pi) + ln w_i + ln w_j + 64 ln2
  float c = -0.5f * muPmu + 0.5f * logdet - 32.f * LN2PI_F
          + logf(wts[i]) + logf(wts[j]) + 64.f * LN2_F;
  float Ev = expf(c);
  if (j <= i)   // packed lower triangle; symmetry factor 2 folded off-diagonal
    ws[WS_ES + i * (i + 1) / 2 + j] = (i == j) ? Ev : 2.f * Ev;
  if (i == j) { // main-loop coefficient row, interleaved {lin_d, Q_dd..Q_d7}
    float* c0 = ws + WS_COEF + i * 48;
    int q = 0;
    #pragma unroll
    for (int d = 0; d < 8; ++d) {
      c0[q++] = pi[64 + d] * LOG2E_F;                 // lin_d
      #pragma unroll
      for (int e = d; e < 8; ++e) {
        float v = (d == e) ? -0.5f * pi[d * 8 + e] : -pi[d * 8 + e];
        c0[q++] = v * LOG2E_F;                        // Q_de
      }
    }
    c0[44] = 0.f; c0[45] = 0.f; c0[46] = 0.f; c0[47] = 0.f;
  }
  if (p == 255) ws[WS_K] = 0.5f * logdet - 32.f * LN2PI_F - 64.f * LN2_F;
}

// ---------------------------------------------------------------------------
// Kernel B: main N-loop, 4 points per thread. The 904-float constant table is
// staged into LDS once per block; inner loops read it via ds_read broadcasts
// (all lanes same address -> conflict-free), which pipeline instead of the
// serial SMEM lgkmcnt chains. Partials written through a disjoint pointer.
// ---------------------------------------------------------------------------
__global__ __launch_bounds__(256) void gm_main(const float* __restrict__ X,
                                               const float* __restrict__ cf,
                                               float* __restrict__ partials,
                                               int N) {
  __shared__ float sc[WS_NSC];   // [0,768) coef rows; [768,904) packed E
  for (int t = threadIdx.x; t < WS_NSC; t += 256) sc[t] = cf[t];

  const int t = threadIdx.x;
  const int base = blockIdx.x * 1024 + t;
  float xs[4][8];
  bool act[4];
  #pragma unroll
  for (int g = 0; g < 4; ++g) {
    int gid = base + g * 256;
    act[g] = gid < N;
    int src = act[g] ? gid : 0;            // clamp: X[0..7] is valid memory
    const float4* Xv = reinterpret_cast<const float4*>(X) + (size_t)src * 2;
    float4 a = Xv[0], b = Xv[1];
    xs[g][0] = a.x; xs[g][1] = a.y; xs[g][2] = a.z; xs[g][3] = a.w;
    xs[g][4] = b.x; xs[g][5] = b.y; xs[g][6] = b.z; xs[g][7] = b.w;
  }
  __syncthreads();                          // staging complete

  // u[g][i] = exp(g_i(x_g)) with log2e pre-folded into coefficients
  float u[4][16];
  #pragma unroll
  for (int i = 0; i < 16; ++i) {
    const float* c = sc + i * 48;
    float g0 = 0.f, g1 = 0.f, g2 = 0.f, g3 = 0.f;
    int q = 0;
    #pragma unroll
    for (int d = 0; d < 8; ++d) {
      float lc = c[q++];
      float r0 = lc, r1 = lc, r2 = lc, r3 = lc;   // lin_d
      #pragma unroll
      for (int e = d; e < 8; ++e) {
        float cc = c[q++];
        r0 = fmaf(cc, xs[0][e], r0);
        r1 = fmaf(cc, xs[1][e], r1);
        r2 = fmaf(cc, xs[2][e], r2);
        r3 = fmaf(cc, xs[3][e], r3);
      }
      g0 = fmaf(xs[0][d], r0, g0);
      g1 = fmaf(xs[1][d], r1, g1);
      g2 = fmaf(xs[2][d], r2, g2);
      g3 = fmaf(xs[3][d], r3, g3);
    }
    u[0][i] = fexp2(g0);
    u[1][i] = fexp2(g1);
    u[2][i] = fexp2(g2);
    u[3][i] = fexp2(g3);
  }

  // pdf = sum_i u_i * ( sum_{j<i} 2E_ij u_j + E_ii u_i )   [E symmetric]
  float p0 = 0.f, p1 = 0.f, p2 = 0.f, p3 = 0.f;
  #pragma unroll
  for (int i = 0; i < 16; ++i) {
    const float* e = sc + WS_ES + (i * (i + 1)) / 2;
    float s0 = 0.f, s1 = 0.f, s2 = 0.f, s3 = 0.f;
    #pragma unroll
    for (int j = 0; j <= i; ++j) {
      float ev = e[j];
      s0 = fmaf(ev, u[0][j], s0);
      s1 = fmaf(ev, u[1][j], s1);
      s2 = fmaf(ev, u[2][j], s2);
      s3 = fmaf(ev, u[3][j], s3);
    }
    p0 = fmaf(u[0][i], s0, p0);
    p1 = fmaf(u[1][i], s1, p1);
    p2 = fmaf(u[2][i], s2, p2);
    p3 = fmaf(u[3][i], s3, p3);
  }
  float lsum = 0.f;
  if (act[0]) lsum += flog2(p0);
  if (act[1]) lsum += flog2(p1);
  if (act[2]) lsum += flog2(p2);
  if (act[3]) lsum += flog2(p3);

  // deterministic block reduction of sum(log2 pdf)
  #pragma unroll
  for (int off = 32; off > 0; off >>= 1) lsum += __shfl_down(lsum, off, 64);
  __shared__ float wsum[4];
  int lane = threadIdx.x & 63, wid = threadIdx.x >> 6;
  if (lane == 0) wsum[wid] = lsum;
  __syncthreads();
  if (threadIdx.x == 0)
    partials[blockIdx.x] = (wsum[0] + wsum[1]) + (wsum[2] + wsum[3]);
}

// ---------------------------------------------------------------------------
// Kernel C: deterministic final reduction (fixed-order strided + tree)
// ---------------------------------------------------------------------------
__global__ __launch_bounds__(256) void gm_final(const float* __restrict__ ws,
                                                float* __restrict__ out,
                                                int nb, float invN) {
  const float* partials = ws + WS_PART;
  float s = 0.f;
  for (int t = threadIdx.x; t < nb; t += 256) s += partials[t];
  #pragma unroll
  for (int off = 32; off > 0; off >>= 1) s += __shfl_down(s, off, 64);
  __shared__ float wsum[4];
  int lane = threadIdx.x & 63, wid = threadIdx.x >> 6;
  if (lane == 0) wsum[wid] = s;
  __syncthreads();
  if (threadIdx.x == 0) {
    float tot = (wsum[0] + wsum[1]) + (wsum[2] + wsum[3]);
    // mean(ln pdf_true) + ln z_last = ln2 * mean(log2 pdf_scaled) + Kconst
    out[0] = tot * LN2_F * invN + ws[WS_K];
  }
}

extern "C" void kernel_launch(void* const* d_in, const int* in_sizes, int n_in,
                              void* d_out, int out_size, void* d_ws, size_t ws_size,
                              hipStream_t stream) {
  const float* X = (const float*)d_in[0];
  const float* mu = (const float*)d_in[1];
  const float* L = (const float*)d_in[2];
  const float* wts = (const float*)d_in[3];
  // d_in[4] ("it") is unused by the reference math.
  float* ws = (float*)d_ws;
  float* out = (float*)d_out;
  int N = in_sizes[0] / 8;
  int nb = (N + 1023) / 1024;            // 4 points per thread, 256 threads
  gm_setup<<<1, 256, 0, stream>>>(mu, L, wts, ws);
  gm_main<<<nb, 256, 0, stream>>>(X, ws, ws + WS_PART, N);
  gm_final<<<1, 256, 0, stream>>>(ws, out, nb, 1.0f / (float)N);
}